// Round 12
// baseline (29.458 us; speedup 1.0000x reference)
//
#include <hip/hip_runtime.h>

typedef __fp16 h2 __attribute__((ext_vector_type(2)));
typedef __fp16 h4 __attribute__((ext_vector_type(4)));
typedef __fp16 h8 __attribute__((ext_vector_type(8)));
typedef float  f4 __attribute__((ext_vector_type(4)));
typedef float  f2 __attribute__((ext_vector_type(2)));

#if __has_builtin(__builtin_amdgcn_fdot2)
#define FDOT2(a, b, c) __builtin_amdgcn_fdot2((a), (b), (c), false)
#else
#define FDOT2(a, b, c) ((c) + (float)(a)[0] * (float)(b)[0] + (float)(a)[1] * (float)(b)[1])
#endif

#define SPB 16
#define NT  640   // 40 threads/sample: (row 0..9) x (e4 0..3); 10 waves/block

// lane^1 exchange on the VALU pipe (quad_perm [1,0,3,2]), no LDS traffic
__device__ __forceinline__ float dpp_xor1(float x) {
    int i = __builtin_amdgcn_mov_dpp(__float_as_int(x), 0xB1, 0xF, 0xF, true);
    return __int_as_float(i);
}

// LDS:
//  X  [160][32] fp16 : x rows, K-padded: [20 data][1.0 bias][11 zeros]
//  WT [96][32]  fp16 : W^T rows, 32-row sections (q/k/v), cols 0..20 valid
//  QKV[160][72] fp16 : per x-row [q 0..23][k 24..47][v 48..71] (pads exact zero)
struct SMa {
    __fp16 X [160 * 32];    // 10240 B
    __fp16 WT[96 * 32];     //  6144 B
};
union UHead { SMa a; float sout[SPB * 210]; };   // 13440 B <= 16384 B alias

__global__ __launch_bounds__(NT, 8)
void crazy_attn_kernel(const float* __restrict__ state,      // (B,100)
                       const float* __restrict__ pos_intra,  // (10,1)
                       const float* __restrict__ wq_i, const float* __restrict__ bq_i,
                       const float* __restrict__ wk_i, const float* __restrict__ bk_i,
                       const float* __restrict__ wv_i, const float* __restrict__ bv_i,
                       const float* __restrict__ pos_inter,  // (10,20)
                       const float* __restrict__ wq, const float* __restrict__ bq,
                       const float* __restrict__ wk, const float* __restrict__ bk,
                       const float* __restrict__ wv, const float* __restrict__ bv,
                       float* __restrict__ out, int B)
{
    __shared__ UHead uh;
    __shared__ __fp16 QKV[160 * 72];   // 23040 B (total 39424 B; 3 blocks/CU wave-capped)

    const int tid  = threadIdx.x;
    const int samp = tid / 40;              // 0..15
    const int u    = tid - samp * 40;
    const int r    = u >> 2;                // frame == inter row
    const int e4   = u & 3;                 // (head, query-parity) in stage A
    const int gs   = blockIdx.x * SPB + samp;
    const int gsc  = (gs < B) ? gs : (B - 1);

    // ---- stage 0: W^T -> LDS (fp16, 32-row sections, bias at k=20) ----
    if (tid < 96) {
        const int sec = tid >> 5, within = tid & 31;   // sec 0=q 1=k 2=v
        const bool valid = within < 21;
        const float* W  = (sec == 1) ? wk : (sec == 2) ? wv : wq;
        const float* Bb = (sec == 1) ? bk : (sec == 2) ? bv : bq;
        union { uint4 u4[4]; h2 hh[16]; } T;
        #pragma unroll
        for (int p = 0; p < 16; ++p) {
            const int j0 = 2 * p, j1 = 2 * p + 1;
            float lo = 0.f, hi = 0.f;
            if (valid) {
                lo = (j0 < 20) ? W[j0 * 21 + within] : ((j0 == 20) ? Bb[within] : 0.f);
                hi = (j1 < 20) ? W[j1 * 21 + within] : 0.f;
            }
            T.hh[p] = __builtin_amdgcn_cvt_pkrtz(lo, hi);
        }
        uint4* wd = (uint4*)&uh.a.WT[tid * 32];
        wd[0] = T.u4[0]; wd[1] = T.u4[1]; wd[2] = T.u4[2]; wd[3] = T.u4[3];
    }
    __syncthreads();   // B0: WT staged (cheap, before the exp-heavy phase)

    // ---- stage A: intra attention; e4 = (head h, query-parity sh) ----
    // Each thread: 5 queries (s = 2*si+sh) of ONE head -> 50 exps.
    {
        const float* sp = state + (size_t)gsc * 100 + r * 10;
        float xv[10];
        #pragma unroll
        for (int t2 = 0; t2 < 5; ++t2) {               // float2 loads (8B aligned)
            const f2 v = *(const f2*)&sp[t2 * 2];
            xv[2 * t2]     = v[0] + pos_intra[2 * t2];
            xv[2 * t2 + 1] = v[1] + pos_intra[2 * t2 + 1];
        }
        float xmx = xv[0], xmn = xv[0];
        #pragma unroll
        for (int t = 1; t < 10; ++t) { xmx = fmaxf(xmx, xv[t]); xmn = fminf(xmn, xv[t]); }

        const int h  = e4 >> 1;          // head (runtime -> cndmask selects)
        const int sh = e4 & 1;           // query parity
        const float wqh = h ? wq_i[1] : wq_i[0];
        const float bqh = h ? bq_i[1] : bq_i[0];
        const float wkh = h ? wk_i[1] : wk_i[0];
        const float wvh = h ? wv_i[1] : wv_i[0];
        const float bvh = h ? bv_i[1] : bv_i[0];

        __fp16* xrow = &uh.a.X[(samp * 10 + r) * 32];
        const float* prow = pos_inter + r * 20;
        #pragma unroll
        for (int si = 0; si < 5; ++si) {
            const float c0 = fmaf(xv[2 * si],     wqh, bqh) * wkh;
            const float c1 = fmaf(xv[2 * si + 1], wqh, bqh) * wkh;
            const float c  = sh ? c1 : c0;                 // s = 2*si+sh
            const float mx = c * ((c >= 0.f) ? xmx : xmn); // exact max_t(c*x_t)
            const float cL = c * 1.44269504f;
            const float mL = mx * 1.44269504f;
            float S0 = 0.f, S1 = 0.f;
            #pragma unroll
            for (int t = 0; t < 10; ++t) {
                const float ex = __builtin_amdgcn_exp2f(fmaf(cL, xv[t], -mL));
                S0 += ex; S1 = fmaf(ex, xv[t], S1);
            }
            // o/sum = wv*(S1/S0) + bv  (v-projection folded out of the loop)
            const float res = fmaf(wvh, S1 * __builtin_amdgcn_rcpf(S0), bvh);
            const int k = 4 * si + 2 * sh + h;             // feature index
            xrow[k] = (__fp16)(res + prow[k]);
        }
        // pads k=20..31 (bias 1.0 at k=20), 3 fp16 per thread
        #pragma unroll
        for (int j = 0; j < 3; ++j) {
            const int k = 20 + 4 * j + e4;
            xrow[k] = (__fp16)((k == 20) ? 1.0f : 0.0f);
        }
    }

    // ---- stage B (fused, NO barrier): wave w's stage-A rows 16w..16w+15 are
    // exactly proj tile nt=w; same-wave LDS RAW is lgkmcnt-ordered.
    // D(96x160) = WT(96x32) . X^T(32x160), 6 MFMA/wave
    {
        const int l  = tid & 63;
        const int w  = tid >> 6;        // wave 0..9 == tile
        const int lr = l & 15, lh = l >> 4;
        h8 afrag[6];
        #pragma unroll
        for (int mt = 0; mt < 6; ++mt)
            afrag[mt] = *(const h8*)&uh.a.WT[(mt * 16 + lr) * 32 + lh * 8];
        const int xrow = w * 16 + lr;   // own-wave rows only
        const h8 bfrag = *(const h8*)&uh.a.X[xrow * 32 + lh * 8];
        #pragma unroll
        for (int mt = 0; mt < 6; ++mt) {
            f4 acc = {0.f, 0.f, 0.f, 0.f};
            acc = __builtin_amdgcn_mfma_f32_16x16x32_f16(afrag[mt], bfrag, acc, 0, 0, 0);
            const int m0     = mt * 16 + lh * 4;   // 4 consecutive m per lane
            const int sec    = m0 >> 5;            // 0=q 1=k 2=v
            const int within = m0 & 31;
            if (within <= 20) {                    // cols 21..23 are exact zeros
                union { h2 p2[2]; h4 p4; } P;
                P.p2[0] = __builtin_amdgcn_cvt_pkrtz(acc[0], acc[1]);
                P.p2[1] = __builtin_amdgcn_cvt_pkrtz(acc[2], acc[3]);
                *(h4*)&QKV[xrow * 72 + sec * 24 + within] = P.p4;
            }
        }
    }
    __syncthreads();   // B2: QKV staged; X/WT dead -> sout alias safe

    // ---- stage C: inter attention on half-lanes (e4<2); e splits K/V tiles
    if (e4 < 2) {
        const int e = e4;
        const __fp16* samprows = &QKV[samp * 720];
        union { uint4 u4[3]; h2 hh[12]; } Q;
        {
            const uint4* qsrc = (const uint4*)&samprows[r * 72];    // cols 0..23
            Q.u4[0] = qsrc[0]; Q.u4[1] = qsrc[1]; Q.u4[2] = qsrc[2];
        }
        float mysc[5];
        #pragma unroll
        for (int i = 0; i < 5; ++i) {
            const int t = 2 * i + e;
            union { uint4 u4[3]; h2 hh[12]; } K;
            const uint4* ks = (const uint4*)&samprows[t * 72 + 24]; // cols 24..47
            K.u4[0] = ks[0]; K.u4[1] = ks[1]; K.u4[2] = ks[2];
            float d = 0.f;
            #pragma unroll
            for (int p = 0; p < 11; ++p) d = FDOT2(Q.hh[p], K.hh[p], d);
            mysc[i] = d * 0.21821789023599239f;   // 1/sqrt(21)
        }
        // cross-e softmax: max and sum via DPP xor-1 (lanes 4r,4r+1 both active)
        float mymax = mysc[0];
        #pragma unroll
        for (int i = 1; i < 5; ++i) mymax = fmaxf(mymax, mysc[i]);
        const float m = fmaxf(mymax, dpp_xor1(mymax));
        float pe[5], psum = 0.f;
        #pragma unroll
        for (int i = 0; i < 5; ++i) {
            pe[i] = __builtin_amdgcn_exp2f((mysc[i] - m) * 1.44269504f);
            psum += pe[i];
        }
        const float sum = psum + dpp_xor1(psum);
        const float inv = __builtin_amdgcn_rcpf(sum);

        float acc[21];
        #pragma unroll
        for (int c = 0; c < 21; ++c) acc[c] = 0.f;
        #pragma unroll
        for (int i = 0; i < 5; ++i) {
            const int t = 2 * i + e;
            union { uint4 u4[3]; h2 hh[12]; } V;
            const uint4* vs = (const uint4*)&samprows[t * 72 + 48]; // cols 48..71
            V.u4[0] = vs[0]; V.u4[1] = vs[1]; V.u4[2] = vs[2];
            const float a = pe[i] * inv;
            #pragma unroll
            for (int c = 0; c < 21; ++c)
                acc[c] = fmaf(a, (float)V.hh[c >> 1][c & 1], acc[c]);  // v_fma_mix
        }
        // cross-e reduce via DPP; e0 lane writes the row
        #pragma unroll
        for (int c = 0; c < 21; ++c) acc[c] += dpp_xor1(acc[c]);
        if (e == 0) {
            float* dst = &uh.sout[(samp * 10 + r) * 21];
            #pragma unroll
            for (int c = 0; c < 21; ++c) dst[c] = acc[c];
        }
    }
    __syncthreads();   // B3: sout staged

    // ---- epilogue: coalesced block copy ----
    {
        const int samp0 = blockIdx.x * SPB;
        const int nrem  = B - samp0;
        const int nval  = ((nrem < SPB) ? nrem : SPB) * 210;
        float* gdst = out + (size_t)samp0 * 210;
        if (nval == SPB * 210) {
            for (int i = tid; i < SPB * 210 / 4; i += NT)
                ((f4*)gdst)[i] = ((const f4*)uh.sout)[i];
        } else {
            for (int i = tid; i < nval; i += NT) gdst[i] = uh.sout[i];
        }
    }
}

extern "C" void kernel_launch(void* const* d_in, const int* in_sizes, int n_in,
                              void* d_out, int out_size, void* d_ws, size_t ws_size,
                              hipStream_t stream) {
    const float* state     = (const float*)d_in[0];
    const float* pos_intra = (const float*)d_in[1];
    const float* wq_i      = (const float*)d_in[2];
    const float* bq_i      = (const float*)d_in[3];
    const float* wk_i      = (const float*)d_in[4];
    const float* bk_i      = (const float*)d_in[5];
    const float* wv_i      = (const float*)d_in[6];
    const float* bv_i      = (const float*)d_in[7];
    const float* pos_inter = (const float*)d_in[8];
    const float* wq        = (const float*)d_in[9];
    const float* bq        = (const float*)d_in[10];
    const float* wk        = (const float*)d_in[11];
    const float* bk        = (const float*)d_in[12];
    const float* wv        = (const float*)d_in[13];
    const float* bv        = (const float*)d_in[14];
    float* outp = (float*)d_out;

    const int B = in_sizes[0] / 100;
    const int grid = (B + SPB - 1) / SPB;
    hipLaunchKernelGGL(crazy_attn_kernel, dim3(grid), dim3(NT), 0, stream,
                       state, pos_intra, wq_i, bq_i, wk_i, bk_i, wv_i, bv_i,
                       pos_inter, wq, bq, wk, bk, wv, bv, outp, B);
}

// Round 13
// 22.481 us; speedup vs baseline: 1.3103x; 1.3103x over previous
//
#include <hip/hip_runtime.h>

typedef __fp16 h2 __attribute__((ext_vector_type(2)));
typedef __fp16 h4 __attribute__((ext_vector_type(4)));
typedef __fp16 h8 __attribute__((ext_vector_type(8)));
typedef float  f4 __attribute__((ext_vector_type(4)));
typedef float  f2 __attribute__((ext_vector_type(2)));

#if __has_builtin(__builtin_amdgcn_fdot2)
#define FDOT2(a, b, c) __builtin_amdgcn_fdot2((a), (b), (c), false)
#else
#define FDOT2(a, b, c) ((c) + (float)(a)[0] * (float)(b)[0] + (float)(a)[1] * (float)(b)[1])
#endif

#define SPB 16
#define NT  320   // 20 threads/sample: (row 0..9) x (e 0..1); 5 waves/block

// lane^1 exchange on the VALU pipe (quad_perm [1,0,3,2]), no LDS traffic
__device__ __forceinline__ float dpp_xor1(float x) {
    int i = __builtin_amdgcn_mov_dpp(__float_as_int(x), 0xB1, 0xF, 0xF, true);
    return __int_as_float(i);
}

// LDS:
//  X  [160][32] fp16 : x rows, K-padded: [20 data][1.0 bias][11 zeros]
//  WT [96][32]  fp16 : W^T rows, 32-row sections (q/k/v), cols 0..20 valid
//  QKV[160][72] fp16 : per x-row [q 0..23][k 24..47][v 48..71] (pads exact zero)
struct SMa {
    __fp16 X [160 * 32];    // 10240 B
    __fp16 WT[96 * 32];     //  6144 B
};
union UHead { SMa a; float sout[SPB * 210]; };   // 13440 B <= 16384 B alias

__global__ __launch_bounds__(NT, 5)
void crazy_attn_kernel(const float* __restrict__ state,      // (B,100)
                       const float* __restrict__ pos_intra,  // (10,1)
                       const float* __restrict__ wq_i, const float* __restrict__ bq_i,
                       const float* __restrict__ wk_i, const float* __restrict__ bk_i,
                       const float* __restrict__ wv_i, const float* __restrict__ bv_i,
                       const float* __restrict__ pos_inter,  // (10,20)
                       const float* __restrict__ wq, const float* __restrict__ bq,
                       const float* __restrict__ wk, const float* __restrict__ bk,
                       const float* __restrict__ wv, const float* __restrict__ bv,
                       float* __restrict__ out, int B)
{
    __shared__ UHead uh;
    __shared__ __fp16 QKV[160 * 72];   // 23040 B (total 39424 B -> 4 blocks/CU)

    const int tid  = threadIdx.x;
    const int e    = tid & 1;               // pair lane (xor-1 partner)
    const int rr   = (tid >> 1) % 10;       // frame == inter row
    const int samp = tid / 20;              // 0..15
    const int gs   = blockIdx.x * SPB + samp;
    const int gsc  = (gs < B) ? gs : (B - 1);

    // ---- hoisted stage-A inputs: issue state loads BEFORE the weight barrier
    // (independent of LDS; latency overlaps stage-0's scattered weight loads)
    float xv[10];
    {
        const float* sp = state + (size_t)gsc * 100 + rr * 10;
        #pragma unroll
        for (int t2 = 0; t2 < 5; ++t2) {               // float2 loads (8B aligned)
            const f2 v = *(const f2*)&sp[t2 * 2];
            xv[2 * t2]     = v[0] + pos_intra[2 * t2];
            xv[2 * t2 + 1] = v[1] + pos_intra[2 * t2 + 1];
        }
    }
    float xmx = xv[0], xmn = xv[0];
    #pragma unroll
    for (int t = 1; t < 10; ++t) { xmx = fmaxf(xmx, xv[t]); xmn = fminf(xmn, xv[t]); }

    // ---- stage 0: W^T -> LDS (fp16, 32-row sections, bias at k=20) ----
    if (tid < 96) {
        const int sec = tid >> 5, within = tid & 31;   // sec 0=q 1=k 2=v
        const bool valid = within < 21;
        const float* W  = (sec == 1) ? wk : (sec == 2) ? wv : wq;
        const float* Bb = (sec == 1) ? bk : (sec == 2) ? bv : bq;
        union { uint4 u4[4]; h2 hh[16]; } T;
        #pragma unroll
        for (int p = 0; p < 16; ++p) {
            const int j0 = 2 * p, j1 = 2 * p + 1;
            float lo = 0.f, hi = 0.f;
            if (valid) {
                lo = (j0 < 20) ? W[j0 * 21 + within] : ((j0 == 20) ? Bb[within] : 0.f);
                hi = (j1 < 20) ? W[j1 * 21 + within] : 0.f;
            }
            T.hh[p] = __builtin_amdgcn_cvt_pkrtz(lo, hi);
        }
        uint4* wd = (uint4*)&uh.a.WT[tid * 32];
        wd[0] = T.u4[0]; wd[1] = T.u4[1]; wd[2] = T.u4[2]; wd[3] = T.u4[3];
    }
    __syncthreads();   // B0: WT staged

    // ---- stage A: intra attention; e splits query rows (s = 2*si + e) ----
    {
        float res[2][5];   // [h][si]
        #pragma unroll
        for (int h = 0; h < 2; ++h) {
            const float wqh = wq_i[h], bqh = bq_i[h];
            const float wkh = wk_i[h];
            const float wvh = wv_i[h], bvh = bv_i[h];
            float vh[10];
            #pragma unroll
            for (int t = 0; t < 10; ++t) vh[t] = fmaf(xv[t], wvh, bvh);
            #pragma unroll
            for (int si = 0; si < 5; ++si) {
                const float c0 = fmaf(xv[2 * si],     wqh, bqh) * wkh;
                const float c1 = fmaf(xv[2 * si + 1], wqh, bqh) * wkh;
                const float c  = e ? c1 : c0;                      // s = 2*si+e
                const float mx = c * ((c >= 0.f) ? xmx : xmn);     // exact max
                const float cL = c * 1.44269504f;
                const float mL = mx * 1.44269504f;
                // 2-way split accumulators: halve the dependent-chain depth
                float s0a = 0.f, s0b = 0.f, o0a = 0.f, o0b = 0.f;
                #pragma unroll
                for (int t = 0; t < 5; ++t) {
                    const float ea_ = __builtin_amdgcn_exp2f(fmaf(cL, xv[2 * t],     -mL));
                    const float eb_ = __builtin_amdgcn_exp2f(fmaf(cL, xv[2 * t + 1], -mL));
                    s0a += ea_;                  s0b += eb_;
                    o0a = fmaf(ea_, vh[2 * t], o0a);
                    o0b = fmaf(eb_, vh[2 * t + 1], o0b);
                }
                res[h][si] = (o0a + o0b) * __builtin_amdgcn_rcpf(s0a + s0b);
            }
        }
        // write 5 feature-pairs (k = 2s, 2s+1), s = 2*si+e
        __fp16* xrow = &uh.a.X[(samp * 10 + rr) * 32];
        const float* prow = pos_inter + rr * 20;
        #pragma unroll
        for (int si = 0; si < 5; ++si) {
            const int s = 2 * si + e;
            *(h2*)&xrow[2 * s] = __builtin_amdgcn_cvt_pkrtz(res[0][si] + prow[2 * s],
                                                            res[1][si] + prow[2 * s + 1]);
        }
        // pads: e0 -> pairs k=20(bias),22,24 ; e1 -> 26,28,30
        const h2 z  = __builtin_amdgcn_cvt_pkrtz(0.f, 0.f);
        const h2 bz = __builtin_amdgcn_cvt_pkrtz(1.0f, 0.f);
        #pragma unroll
        for (int j = 0; j < 3; ++j) {
            const int k = 20 + 2 * (3 * e + j);
            *(h2*)&xrow[k] = (e == 0 && j == 0) ? bz : z;
        }
    }

    // ---- stage B (fused, NO barrier): wave w's stage-A rows 32w..32w+31 are
    // exactly proj tiles nt=2w,2w+1; same-wave LDS RAW is lgkmcnt-ordered.
    // D(96x160) = WT(96x32) . X^T(32x160), 12 MFMA/wave
    {
        const int l  = tid & 63;
        const int w  = tid >> 6;        // wave 0..4
        const int lr = l & 15, lh = l >> 4;
        h8 afrag[6];
        #pragma unroll
        for (int mt = 0; mt < 6; ++mt)
            afrag[mt] = *(const h8*)&uh.a.WT[(mt * 16 + lr) * 32 + lh * 8];
        #pragma unroll
        for (int i = 0; i < 2; ++i) {
            const int xrow = (2 * w + i) * 16 + lr;    // own-wave rows only
            const h8 bfrag = *(const h8*)&uh.a.X[xrow * 32 + lh * 8];
            #pragma unroll
            for (int mt = 0; mt < 6; ++mt) {
                f4 acc = {0.f, 0.f, 0.f, 0.f};
                acc = __builtin_amdgcn_mfma_f32_16x16x32_f16(afrag[mt], bfrag, acc, 0, 0, 0);
                const int m0     = mt * 16 + lh * 4;   // 4 consecutive m per lane
                const int sec    = m0 >> 5;            // 0=q 1=k 2=v
                const int within = m0 & 31;
                if (within <= 20) {                    // cols 21..23 are exact zeros
                    union { h2 p2[2]; h4 p4; } P;
                    P.p2[0] = __builtin_amdgcn_cvt_pkrtz(acc[0], acc[1]);
                    P.p2[1] = __builtin_amdgcn_cvt_pkrtz(acc[2], acc[3]);
                    *(h4*)&QKV[xrow * 72 + sec * 24 + within] = P.p4;
                }
            }
        }
    }
    __syncthreads();   // B2: QKV staged; X/WT dead -> sout alias safe

    // ---- stage C: inter attention; e splits K/V tiles (t = 2i+e) ----
    {
        const __fp16* samprows = &QKV[samp * 10 * 72];
        union { uint4 u4[3]; h2 hh[12]; } Q;
        {
            const uint4* qsrc = (const uint4*)&samprows[rr * 72];   // cols 0..23
            Q.u4[0] = qsrc[0]; Q.u4[1] = qsrc[1]; Q.u4[2] = qsrc[2];
        }
        float mysc[5];
        #pragma unroll
        for (int i = 0; i < 5; ++i) {
            const int t = 2 * i + e;
            union { uint4 u4[3]; h2 hh[12]; } K;
            const uint4* ks = (const uint4*)&samprows[t * 72 + 24]; // cols 24..47
            K.u4[0] = ks[0]; K.u4[1] = ks[1]; K.u4[2] = ks[2];
            float d = 0.f;
            #pragma unroll
            for (int p = 0; p < 11; ++p) d = FDOT2(Q.hh[p], K.hh[p], d);
            mysc[i] = d * 0.21821789023599239f;   // 1/sqrt(21)
        }
        // cross-e softmax: max and sum via DPP xor-1 (no LDS)
        float mymax = mysc[0];
        #pragma unroll
        for (int i = 1; i < 5; ++i) mymax = fmaxf(mymax, mysc[i]);
        const float m = fmaxf(mymax, dpp_xor1(mymax));
        float pe[5], psum = 0.f;
        #pragma unroll
        for (int i = 0; i < 5; ++i) {
            pe[i] = __builtin_amdgcn_exp2f((mysc[i] - m) * 1.44269504f);
            psum += pe[i];
        }
        const float sum = psum + dpp_xor1(psum);
        const float inv = __builtin_amdgcn_rcpf(sum);

        float acc[21];
        #pragma unroll
        for (int c = 0; c < 21; ++c) acc[c] = 0.f;
        #pragma unroll
        for (int i = 0; i < 5; ++i) {
            const int t = 2 * i + e;
            union { uint4 u4[3]; h2 hh[12]; } V;
            const uint4* vs = (const uint4*)&samprows[t * 72 + 48]; // cols 48..71
            V.u4[0] = vs[0]; V.u4[1] = vs[1]; V.u4[2] = vs[2];
            const float a = pe[i] * inv;
            #pragma unroll
            for (int c = 0; c < 21; ++c)
                acc[c] = fmaf(a, (float)V.hh[c >> 1][c & 1], acc[c]);  // v_fma_mix
        }
        // cross-e reduce via DPP; e0 lane writes the row
        #pragma unroll
        for (int c = 0; c < 21; ++c) acc[c] += dpp_xor1(acc[c]);
        if (e == 0) {
            float* dst = &uh.sout[(samp * 10 + rr) * 21];
            #pragma unroll
            for (int c = 0; c < 21; ++c) dst[c] = acc[c];
        }
    }
    __syncthreads();   // B3: sout staged

    // ---- epilogue: coalesced block copy ----
    {
        const int samp0 = blockIdx.x * SPB;
        const int nrem  = B - samp0;
        const int nval  = ((nrem < SPB) ? nrem : SPB) * 210;
        float* gdst = out + (size_t)samp0 * 210;
        if (nval == SPB * 210) {
            for (int i = tid; i < SPB * 210 / 4; i += NT)
                ((f4*)gdst)[i] = ((const f4*)uh.sout)[i];
        } else {
            for (int i = tid; i < nval; i += NT) gdst[i] = uh.sout[i];
        }
    }
}

extern "C" void kernel_launch(void* const* d_in, const int* in_sizes, int n_in,
                              void* d_out, int out_size, void* d_ws, size_t ws_size,
                              hipStream_t stream) {
    const float* state     = (const float*)d_in[0];
    const float* pos_intra = (const float*)d_in[1];
    const float* wq_i      = (const float*)d_in[2];
    const float* bq_i      = (const float*)d_in[3];
    const float* wk_i      = (const float*)d_in[4];
    const float* bk_i      = (const float*)d_in[5];
    const float* wv_i      = (const float*)d_in[6];
    const float* bv_i      = (const float*)d_in[7];
    const float* pos_inter = (const float*)d_in[8];
    const float* wq        = (const float*)d_in[9];
    const float* bq        = (const float*)d_in[10];
    const float* wk        = (const float*)d_in[11];
    const float* bk        = (const float*)d_in[12];
    const float* wv        = (const float*)d_in[13];
    const float* bv        = (const float*)d_in[14];
    float* outp = (float*)d_out;

    const int B = in_sizes[0] / 100;
    const int grid = (B + SPB - 1) / SPB;
    hipLaunchKernelGGL(crazy_attn_kernel, dim3(grid), dim3(NT), 0, stream,
                       state, pos_intra, wq_i, bq_i, wk_i, bk_i, wv_i, bv_i,
                       pos_inter, wq, bq, wk, bk, wv, bv, outp, B);
}